// Round 2
// baseline (11382.604 us; speedup 1.0000x reference)
//
#include <hip/hip_runtime.h>
#include <math.h>

// Problem constants
constexpr int B_    = 512;
constexpr int S_    = 190;   // CODE_N + PC_ROWS
constexpr int D_    = 128;
constexpr int H_    = 8;
constexpr int DK_   = 16;
constexpr int DFF_  = 512;
constexpr int NDEC_ = 10;
constexpr int CN_   = 127;   // CODE_N
constexpr int PCR_  = 63;    // PC_ROWS
constexpr int MR_   = B_ * S_;  // 97280 rows, divisible by 64 and by 4

// bf16 helpers (OCP bf16 = top 16 bits of f32; RNE pack)
__device__ __forceinline__ float blo(unsigned w) { return __uint_as_float(w << 16); }
__device__ __forceinline__ float bhi(unsigned w) { return __uint_as_float(w & 0xffff0000u); }
__device__ __forceinline__ unsigned short f2b(float f) {
    unsigned x = __float_as_uint(f);
    unsigned r = x + 0x7fffu + ((x >> 16) & 1u);
    return (unsigned short)(r >> 16);
}
__device__ __forceinline__ float b2f(unsigned short u) { return __uint_as_float(((unsigned)u) << 16); }

// ---------------------------------------------------------------------------
// Mask: additive float mask, 0 where allowed, -1e9 where blocked.
__global__ void build_mask_k(const int* __restrict__ pc, float* __restrict__ mask) {
    int idx = blockIdx.x * blockDim.x + threadIdx.x;
    if (idx >= S_ * S_) return;
    int i = idx / S_, j = idx % S_;
    bool allow;
    if (i < CN_ && j < CN_) {
        if (i == j) allow = true;
        else {
            allow = false;
            for (int m = 0; m < PCR_; ++m) {
                if (pc[m * CN_ + i] > 0 && pc[m * CN_ + j] > 0) { allow = true; break; }
            }
        }
    } else if (i < CN_) {
        allow = pc[(j - CN_) * CN_ + i] > 0;
    } else if (j < CN_) {
        allow = pc[(i - CN_) * CN_ + j] > 0;
    } else {
        allow = (i == j);
    }
    mask[idx] = allow ? 0.0f : -1e9f;
}

// ---------------------------------------------------------------------------
__global__ void embed_k(const float* __restrict__ mag, const float* __restrict__ syn,
                        const float* __restrict__ se, float* __restrict__ x) {
    long idx = (long)blockIdx.x * blockDim.x + threadIdx.x;
    if (idx >= (long)MR_ * D_) return;
    int d  = (int)(idx & (D_ - 1));
    long bs = idx >> 7;
    int s = (int)(bs % S_);
    int b = (int)(bs / S_);
    float e = (s < CN_) ? mag[b * CN_ + s] : syn[b * PCR_ + (s - CN_)];
    x[idx] = se[s * D_ + d] * e;
}

// ---------------------------------------------------------------------------
// LayerNorm: one wave per row of 128; 4 rows per block. OBF: bf16 output.
template <bool OBF>
__global__ __launch_bounds__(256) void ln_k(const float* __restrict__ in,
                                            const float* __restrict__ g,
                                            const float* __restrict__ bta,
                                            void* __restrict__ outp) {
    int wave = threadIdx.x >> 6;
    int lane = threadIdx.x & 63;
    long row = (long)blockIdx.x * 4 + wave;
    const float* r = in + row * D_;
    float2 v = *(const float2*)(r + lane * 2);
    float sum = v.x + v.y;
    float sq  = v.x * v.x + v.y * v.y;
    #pragma unroll
    for (int o = 32; o; o >>= 1) { sum += __shfl_xor(sum, o); sq += __shfl_xor(sq, o); }
    float mean = sum * (1.0f / D_);
    float var  = sq * (1.0f / D_) - mean * mean;
    float inv  = rsqrtf(var + 1e-5f);
    float2 gv = *(const float2*)(g + lane * 2);
    float2 bv = *(const float2*)(bta + lane * 2);
    float o0 = gv.x * (v.x - mean) * inv + bv.x;
    float o1 = gv.y * (v.y - mean) * inv + bv.y;
    if (OBF) {
        unsigned packed = (unsigned)f2b(o0) | ((unsigned)f2b(o1) << 16);
        *(unsigned*)((unsigned short*)outp + row * D_ + lane * 2) = packed;
    } else {
        float2 ov; ov.x = o0; ov.y = o1;
        *(float2*)((float*)outp + row * D_ + lane * 2) = ov;
    }
}

// ---------------------------------------------------------------------------
// Tiled GEMM: out[M,N] = A[M,K] @ W[K,N] + bias (+gelu) (+res)
// 64x64 tile, BK=32, 256 threads, 4x4 acc per thread. A: f32 or bf16; out: f32 or bf16.
template <bool ABF, bool OBF, bool GELU, bool RESID>
__global__ __launch_bounds__(256) void gemm_k(const void* __restrict__ Ap,
                                              const float* __restrict__ W,
                                              const float* __restrict__ bias,
                                              const float* __restrict__ res,
                                              void* __restrict__ outp,
                                              int K, int N) {
    __shared__ float As_t[32][68];   // [k][row]
    __shared__ float Ws[32][68];     // [k][col]
    const int tid = threadIdx.x;
    const int tx = tid & 15, ty = tid >> 4;
    const long row0 = (long)blockIdx.x * 64;
    const int  col0 = blockIdx.y * 64;

    float acc[4][4] = {};

    const int ra = tid >> 2;            // 0..63
    const int ca = (tid & 3) * 8;       // 0,8,16,24
    const int rw = tid >> 3;            // 0..31
    const int cw = (tid & 7) * 8;       // 0..56

    for (int k0 = 0; k0 < K; k0 += 32) {
        if (ABF) {
            const unsigned short* Ab = (const unsigned short*)Ap;
            uint4 u = *(const uint4*)(Ab + (row0 + ra) * K + k0 + ca);
            As_t[ca + 0][ra] = blo(u.x); As_t[ca + 1][ra] = bhi(u.x);
            As_t[ca + 2][ra] = blo(u.y); As_t[ca + 3][ra] = bhi(u.y);
            As_t[ca + 4][ra] = blo(u.z); As_t[ca + 5][ra] = bhi(u.z);
            As_t[ca + 6][ra] = blo(u.w); As_t[ca + 7][ra] = bhi(u.w);
        } else {
            const float* Af = (const float*)Ap;
            const float* src = Af + (row0 + ra) * K + k0 + ca;
            float4 a0 = *(const float4*)(src);
            float4 a1 = *(const float4*)(src + 4);
            As_t[ca + 0][ra] = a0.x; As_t[ca + 1][ra] = a0.y;
            As_t[ca + 2][ra] = a0.z; As_t[ca + 3][ra] = a0.w;
            As_t[ca + 4][ra] = a1.x; As_t[ca + 5][ra] = a1.y;
            As_t[ca + 6][ra] = a1.z; As_t[ca + 7][ra] = a1.w;
        }
        {
            const float* wsrc = W + (long)(k0 + rw) * N + col0 + cw;
            *(float4*)&Ws[rw][cw]     = *(const float4*)(wsrc);
            *(float4*)&Ws[rw][cw + 4] = *(const float4*)(wsrc + 4);
        }
        __syncthreads();
        #pragma unroll
        for (int kk = 0; kk < 32; ++kk) {
            float4 a4 = *(const float4*)&As_t[kk][ty * 4];
            float4 w4 = *(const float4*)&Ws[kk][tx * 4];
            float af[4] = {a4.x, a4.y, a4.z, a4.w};
            float wf[4] = {w4.x, w4.y, w4.z, w4.w};
            #pragma unroll
            for (int i = 0; i < 4; ++i)
                #pragma unroll
                for (int j = 0; j < 4; ++j)
                    acc[i][j] = fmaf(af[i], wf[j], acc[i][j]);
        }
        __syncthreads();
    }

    #pragma unroll
    for (int i = 0; i < 4; ++i) {
        long row = row0 + ty * 4 + i;
        float vals[4];
        #pragma unroll
        for (int j = 0; j < 4; ++j) {
            int col = col0 + tx * 4 + j;
            float val = acc[i][j] + bias[col];
            if (GELU) val = 0.5f * val * (1.0f + erff(val * 0.70710678118654752f));
            if (RESID) val += res[row * N + col];
            vals[j] = val;
        }
        if (OBF) {
            ushort4 r4;
            r4.x = f2b(vals[0]); r4.y = f2b(vals[1]); r4.z = f2b(vals[2]); r4.w = f2b(vals[3]);
            *(ushort4*)((unsigned short*)outp + row * N + col0 + tx * 4) = r4;
        } else {
            float4 r4; r4.x = vals[0]; r4.y = vals[1]; r4.z = vals[2]; r4.w = vals[3];
            *(float4*)((float*)outp + row * N + col0 + tx * 4) = r4;
        }
    }
}

// ---------------------------------------------------------------------------
// Attention: one block per (b,h). bf16 q/k/v; K/V staged to f32 LDS.
// 95 threads x 2 q-rows, online softmax, recompute scores in PV pass.
__global__ __launch_bounds__(128) void attn_k(const unsigned short* __restrict__ q,
                                              const unsigned short* __restrict__ kg,
                                              const unsigned short* __restrict__ vg,
                                              const float* __restrict__ mask,
                                              unsigned short* __restrict__ o) {
    __shared__ float ks[S_][DK_];
    __shared__ float vs[S_][DK_];
    const int bh = blockIdx.x;
    const int b = bh >> 3, h = bh & 7;
    const long base = (long)b * S_ * D_ + h * DK_;
    const int tid = threadIdx.x;

    for (int idx = tid; idx < S_ * 2; idx += 128) {
        int s = idx >> 1, c8 = (idx & 1) * 8;
        uint4 uk = *(const uint4*)(kg + base + (long)s * D_ + c8);
        uint4 uv = *(const uint4*)(vg + base + (long)s * D_ + c8);
        ks[s][c8 + 0] = blo(uk.x); ks[s][c8 + 1] = bhi(uk.x);
        ks[s][c8 + 2] = blo(uk.y); ks[s][c8 + 3] = bhi(uk.y);
        ks[s][c8 + 4] = blo(uk.z); ks[s][c8 + 5] = bhi(uk.z);
        ks[s][c8 + 6] = blo(uk.w); ks[s][c8 + 7] = bhi(uk.w);
        vs[s][c8 + 0] = blo(uv.x); vs[s][c8 + 1] = bhi(uv.x);
        vs[s][c8 + 2] = blo(uv.y); vs[s][c8 + 3] = bhi(uv.y);
        vs[s][c8 + 4] = blo(uv.z); vs[s][c8 + 5] = bhi(uv.z);
        vs[s][c8 + 6] = blo(uv.w); vs[s][c8 + 7] = bhi(uv.w);
    }
    __syncthreads();
    if (tid >= 95) return;

    const int i0 = tid, i1 = tid + 95;
    float q0[DK_], q1[DK_];
    #pragma unroll
    for (int d = 0; d < DK_; d += 8) {
        uint4 u0 = *(const uint4*)(q + base + (long)i0 * D_ + d);
        uint4 u1 = *(const uint4*)(q + base + (long)i1 * D_ + d);
        q0[d+0]=blo(u0.x); q0[d+1]=bhi(u0.x); q0[d+2]=blo(u0.y); q0[d+3]=bhi(u0.y);
        q0[d+4]=blo(u0.z); q0[d+5]=bhi(u0.z); q0[d+6]=blo(u0.w); q0[d+7]=bhi(u0.w);
        q1[d+0]=blo(u1.x); q1[d+1]=bhi(u1.x); q1[d+2]=blo(u1.y); q1[d+3]=bhi(u1.y);
        q1[d+4]=blo(u1.z); q1[d+5]=bhi(u1.z); q1[d+6]=blo(u1.w); q1[d+7]=bhi(u1.w);
    }

    float m0 = -1e30f, m1 = -1e30f, l0 = 0.0f, l1 = 0.0f;
    for (int j = 0; j < S_; ++j) {
        float kj[DK_];
        #pragma unroll
        for (int d = 0; d < DK_; d += 4) *(float4*)&kj[d] = *(const float4*)&ks[j][d];
        float s0 = 0.0f, s1 = 0.0f;
        #pragma unroll
        for (int d = 0; d < DK_; ++d) { s0 = fmaf(q0[d], kj[d], s0); s1 = fmaf(q1[d], kj[d], s1); }
        s0 = s0 * 0.25f + mask[i0 * S_ + j];
        s1 = s1 * 0.25f + mask[i1 * S_ + j];
        float nm0 = fmaxf(m0, s0), nm1 = fmaxf(m1, s1);
        l0 = l0 * __expf(m0 - nm0) + __expf(s0 - nm0);
        l1 = l1 * __expf(m1 - nm1) + __expf(s1 - nm1);
        m0 = nm0; m1 = nm1;
    }

    float acc0[DK_] = {}, acc1[DK_] = {};
    for (int j = 0; j < S_; ++j) {
        float kj[DK_], vj[DK_];
        #pragma unroll
        for (int d = 0; d < DK_; d += 4) {
            *(float4*)&kj[d] = *(const float4*)&ks[j][d];
            *(float4*)&vj[d] = *(const float4*)&vs[j][d];
        }
        float s0 = 0.0f, s1 = 0.0f;
        #pragma unroll
        for (int d = 0; d < DK_; ++d) { s0 = fmaf(q0[d], kj[d], s0); s1 = fmaf(q1[d], kj[d], s1); }
        s0 = s0 * 0.25f + mask[i0 * S_ + j];
        s1 = s1 * 0.25f + mask[i1 * S_ + j];
        float p0 = __expf(s0 - m0), p1 = __expf(s1 - m1);
        #pragma unroll
        for (int d = 0; d < DK_; ++d) {
            acc0[d] = fmaf(p0, vj[d], acc0[d]);
            acc1[d] = fmaf(p1, vj[d], acc1[d]);
        }
    }

    const float r0 = 1.0f / l0, r1 = 1.0f / l1;
    #pragma unroll
    for (int d = 0; d < DK_; d += 4) {
        ushort4 w0, w1;
        w0.x = f2b(acc0[d] * r0); w0.y = f2b(acc0[d+1] * r0);
        w0.z = f2b(acc0[d+2] * r0); w0.w = f2b(acc0[d+3] * r0);
        w1.x = f2b(acc1[d] * r1); w1.y = f2b(acc1[d+1] * r1);
        w1.z = f2b(acc1[d+2] * r1); w1.w = f2b(acc1[d+3] * r1);
        *(ushort4*)(o + base + (long)i0 * D_ + d) = w0;
        *(ushort4*)(o + base + (long)i1 * D_ + d) = w1;
    }
}

// ---------------------------------------------------------------------------
__global__ __launch_bounds__(256) void fin_k(const float* __restrict__ x,
                                             const float* __restrict__ g,
                                             const float* __restrict__ bta,
                                             const float* __restrict__ fw,
                                             const float* __restrict__ fb,
                                             float* __restrict__ t) {
    int wave = threadIdx.x >> 6;
    int lane = threadIdx.x & 63;
    long row = (long)blockIdx.x * 4 + wave;
    const float* r = x + row * D_;
    float2 v = *(const float2*)(r + lane * 2);
    float sum = v.x + v.y;
    float sq  = v.x * v.x + v.y * v.y;
    #pragma unroll
    for (int o = 32; o; o >>= 1) { sum += __shfl_xor(sum, o); sq += __shfl_xor(sq, o); }
    float mean = sum * (1.0f / D_);
    float var  = sq * (1.0f / D_) - mean * mean;
    float inv  = rsqrtf(var + 1e-5f);
    float2 gv = *(const float2*)(g + lane * 2);
    float2 bv = *(const float2*)(bta + lane * 2);
    float y0 = gv.x * (v.x - mean) * inv + bv.x;
    float y1 = gv.y * (v.y - mean) * inv + bv.y;
    float part = y0 * fw[lane * 2] + y1 * fw[lane * 2 + 1];
    #pragma unroll
    for (int o = 32; o; o >>= 1) part += __shfl_xor(part, o);
    if (lane == 0) t[row] = part + fb[0];
}

__global__ __launch_bounds__(128) void outgemm_k(const float* __restrict__ t,
                                                 const float* __restrict__ ow,
                                                 const float* __restrict__ ob,
                                                 float* __restrict__ out) {
    __shared__ float ts[S_];
    int b = blockIdx.x, tid = threadIdx.x;
    for (int i = tid; i < S_; i += 128) ts[i] = t[(long)b * S_ + i];
    __syncthreads();
    if (tid < CN_) {
        float acc = ob[tid];
        for (int s = 0; s < S_; ++s) acc = fmaf(ts[s], ow[s * CN_ + tid], acc);
        out[(long)b * CN_ + tid] = acc;
    }
}

// ---------------------------------------------------------------------------
extern "C" void kernel_launch(void* const* d_in, const int* in_sizes, int n_in,
                              void* d_out, int out_size, void* d_ws, size_t ws_size,
                              hipStream_t stream) {
    const float* mag  = (const float*)d_in[0];
    const float* syn  = (const float*)d_in[1];
    const int*   pc   = (const int*)  d_in[2];
    const float* se   = (const float*)d_in[3];
    const float* Wq   = (const float*)d_in[4];
    const float* bq   = (const float*)d_in[5];
    const float* Wk   = (const float*)d_in[6];
    const float* bk   = (const float*)d_in[7];
    const float* Wv   = (const float*)d_in[8];
    const float* bv   = (const float*)d_in[9];
    const float* Wo   = (const float*)d_in[10];
    const float* bo   = (const float*)d_in[11];
    const float* W1   = (const float*)d_in[12];
    const float* b1   = (const float*)d_in[13];
    const float* W2   = (const float*)d_in[14];
    const float* b2   = (const float*)d_in[15];
    const float* ln1g = (const float*)d_in[16];
    const float* ln1b = (const float*)d_in[17];
    const float* ln2g = (const float*)d_in[18];
    const float* ln2b = (const float*)d_in[19];
    const float* encg = (const float*)d_in[20];
    const float* encb = (const float*)d_in[21];
    const float* n2g  = (const float*)d_in[22];
    const float* n2b  = (const float*)d_in[23];
    const float* finw = (const float*)d_in[24];
    const float* finb = (const float*)d_in[25];
    const float* outw = (const float*)d_in[26];
    const float* outb = (const float*)d_in[27];
    float* out = (float*)d_out;

    // Workspace layout in bytes (X = MR*D elements = 12,451,840):
    //   [0,        4X)  x    f32
    //   [4X,       6X)  h/o  bf16
    //   [6X,       8X)  q    bf16   \
    //   [8X,      10X)  k    bf16    } aliased by ff1 bf16 [6X, 14X)
    //   [10X,     12X)  v    bf16   /
    //   [14X, +mask+t)  mask f32, t f32
    // Total ~167 MiB.
    const long X = (long)MR_ * D_;
    char* base = (char*)d_ws;
    float*          x    = (float*)base;
    unsigned short* h    = (unsigned short*)(base + 4 * X);
    unsigned short* q    = (unsigned short*)(base + 6 * X);
    unsigned short* k    = (unsigned short*)(base + 8 * X);
    unsigned short* v    = (unsigned short*)(base + 10 * X);
    unsigned short* o    = h;                                   // alias: h dead after qkv
    unsigned short* ff1  = (unsigned short*)(base + 6 * X);     // alias: qkv dead after attn
    float*          mask = (float*)(base + 14 * X);
    float*          t    = mask + S_ * S_;

    build_mask_k<<<(S_ * S_ + 255) / 256, 256, 0, stream>>>(pc, mask);
    embed_k<<<(int)((X + 255) / 256), 256, 0, stream>>>(mag, syn, se, x);

    const dim3 gemmB(256);
    for (int i = 0; i < NDEC_; ++i) {
        ln_k<true><<<MR_ / 4, 256, 0, stream>>>(x, ln1g + i * D_, ln1b + i * D_, h);
        gemm_k<true, true, false, false><<<dim3(MR_ / 64, D_ / 64), gemmB, 0, stream>>>(
            h, Wq + (long)i * D_ * D_, bq + i * D_, nullptr, q, D_, D_);
        gemm_k<true, true, false, false><<<dim3(MR_ / 64, D_ / 64), gemmB, 0, stream>>>(
            h, Wk + (long)i * D_ * D_, bk + i * D_, nullptr, k, D_, D_);
        gemm_k<true, true, false, false><<<dim3(MR_ / 64, D_ / 64), gemmB, 0, stream>>>(
            h, Wv + (long)i * D_ * D_, bv + i * D_, nullptr, v, D_, D_);
        attn_k<<<B_ * H_, 128, 0, stream>>>(q, k, v, mask, o);
        gemm_k<true, false, false, true><<<dim3(MR_ / 64, D_ / 64), gemmB, 0, stream>>>(
            o, Wo + (long)i * D_ * D_, bo + i * D_, x, x, D_, D_);
        ln_k<true><<<MR_ / 4, 256, 0, stream>>>(x, ln2g + i * D_, ln2b + i * D_, h);
        gemm_k<true, true, true, false><<<dim3(MR_ / 64, DFF_ / 64), gemmB, 0, stream>>>(
            h, W1 + (long)i * D_ * DFF_, b1 + i * DFF_, nullptr, ff1, D_, DFF_);
        gemm_k<true, false, false, true><<<dim3(MR_ / 64, DFF_ / 64 * 0 + D_ / 64), gemmB, 0, stream>>>(
            ff1, W2 + (long)i * DFF_ * D_, b2 + i * D_, x, x, DFF_, D_);
        if (i == 4) {
            ln_k<false><<<MR_ / 4, 256, 0, stream>>>(x, n2g, n2b, x);  // row-local, in-place safe
        }
    }

    fin_k<<<MR_ / 4, 256, 0, stream>>>(x, encg, encb, finw, finb, t);
    outgemm_k<<<B_, 128, 0, stream>>>(t, outw, outb, out);
}

// Round 3
// 4581.358 us; speedup vs baseline: 2.4845x; 2.4845x over previous
//
#include <hip/hip_runtime.h>
#include <math.h>

typedef unsigned int uint;
typedef unsigned short ushort;

// Problem constants
constexpr int B_    = 512;
constexpr int S_    = 190;   // CODE_N + PC_ROWS
constexpr int D_    = 128;
constexpr int DFF_  = 512;
constexpr int NDEC_ = 10;
constexpr int CN_   = 127;
constexpr int PCR_  = 63;
constexpr int MR_   = B_ * S_;  // 97280 = 760*128

typedef __attribute__((ext_vector_type(8))) short bf16x8;
typedef __attribute__((ext_vector_type(4))) float f32x4;

// bf16 helpers
__device__ __forceinline__ float blo(uint w) { return __uint_as_float(w << 16); }
__device__ __forceinline__ float bhi(uint w) { return __uint_as_float(w & 0xffff0000u); }
__device__ __forceinline__ ushort f2b(float f) {
    uint x = __float_as_uint(f);
    uint r = x + 0x7fffu + ((x >> 16) & 1u);
    return (ushort)(r >> 16);
}
__device__ __forceinline__ void unpack8(uint4 u, float* f) {
    f[0]=blo(u.x); f[1]=bhi(u.x); f[2]=blo(u.y); f[3]=bhi(u.y);
    f[4]=blo(u.z); f[5]=bhi(u.z); f[6]=blo(u.w); f[7]=bhi(u.w);
}

// ---------------------------------------------------------------------------
// Mask bitmask: mb[i][w] bit b set = position j=w*32+b is ALLOWED.
__device__ bool allow_f(int i, int j, const int* pc) {
    if (i < CN_ && j < CN_) {
        if (i == j) return true;
        for (int m = 0; m < PCR_; ++m)
            if (pc[m * CN_ + i] > 0 && pc[m * CN_ + j] > 0) return true;
        return false;
    } else if (i < CN_) {
        return pc[(j - CN_) * CN_ + i] > 0;
    } else if (j < CN_) {
        return pc[(i - CN_) * CN_ + j] > 0;
    }
    return i == j;
}

__global__ void mbits_k(const int* __restrict__ pc, uint* __restrict__ mb) {
    int idx = blockIdx.x * 256 + threadIdx.x;
    if (idx >= S_ * 8) return;
    int i = idx >> 3, w = idx & 7;
    uint word = 0;
    if (w < 6) {
        for (int b = 0; b < 32; ++b) {
            int j = w * 32 + b;
            if (j < S_ && allow_f(i, j, pc)) word |= (1u << b);
        }
    }
    mb[idx] = word;
}

// ---------------------------------------------------------------------------
__global__ void embed_k(const float* __restrict__ mag, const float* __restrict__ syn,
                        const float* __restrict__ se, float* __restrict__ x) {
    long idx = (long)blockIdx.x * blockDim.x + threadIdx.x;
    if (idx >= (long)MR_ * D_) return;
    int d  = (int)(idx & (D_ - 1));
    long bs = idx >> 7;
    int s = (int)(bs % S_);
    int b = (int)(bs / S_);
    float e = (s < CN_) ? mag[b * CN_ + s] : syn[b * PCR_ + (s - CN_)];
    x[idx] = se[s * D_ + d] * e;
}

// ---------------------------------------------------------------------------
// Weight transpose to bf16 [L][N][K]
__global__ void wtr_k(const float* __restrict__ src, ushort* __restrict__ dst,
                      int K, int N) {
    int idx = blockIdx.x * 256 + threadIdx.x;   // grid sized exactly: 10*K*N/256
    int KN = K * N;
    int l = idx / KN, rem = idx % KN;
    int n = rem / K, k = rem % K;
    dst[idx] = f2b(src[(long)l * KN + (long)k * N + n]);
}

// Fused QKV weight transpose: dst [10][384][128]
__global__ void wtr_qkv_k(const float* __restrict__ Wq, const float* __restrict__ Wk,
                          const float* __restrict__ Wv, ushort* __restrict__ dst) {
    int idx = blockIdx.x * 256 + threadIdx.x;   // 10*384*128 = 491520
    int l = idx / (384 * 128);
    int rem = idx % (384 * 128);
    int n = rem >> 7, k = rem & 127;
    const float* src = (n < 128) ? Wq : (n < 256) ? Wk : Wv;
    dst[idx] = f2b(src[l * 16384 + k * 128 + (n & 127)]);
}

__global__ void bcat_k(const float* __restrict__ bq, const float* __restrict__ bk,
                       const float* __restrict__ bv, float* __restrict__ dst) {
    int idx = blockIdx.x * 256 + threadIdx.x;   // 3840
    int l = idx / 384, n = idx % 384;
    const float* s = (n < 128) ? bq : (n < 256) ? bk : bv;
    dst[idx] = s[l * 128 + (n & 127)];
}

// ---------------------------------------------------------------------------
// LayerNorm: one wave per 128-row; 4 rows/block. OBF: bf16 out.
template <bool OBF>
__global__ __launch_bounds__(256) void ln_k(const float* __restrict__ in,
                                            const float* __restrict__ g,
                                            const float* __restrict__ bta,
                                            void* outp) {
    int wave = threadIdx.x >> 6;
    int lane = threadIdx.x & 63;
    long row = (long)blockIdx.x * 4 + wave;
    const float* r = in + row * D_;
    float2 v = *(const float2*)(r + lane * 2);
    float sum = v.x + v.y;
    float sq  = v.x * v.x + v.y * v.y;
    #pragma unroll
    for (int o = 32; o; o >>= 1) { sum += __shfl_xor(sum, o); sq += __shfl_xor(sq, o); }
    float mean = sum * (1.0f / D_);
    float var  = sq * (1.0f / D_) - mean * mean;
    float inv  = rsqrtf(var + 1e-5f);
    float2 gv = *(const float2*)(g + lane * 2);
    float2 bv = *(const float2*)(bta + lane * 2);
    float o0 = gv.x * (v.x - mean) * inv + bv.x;
    float o1 = gv.y * (v.y - mean) * inv + bv.y;
    if (OBF) {
        uint packed = (uint)f2b(o0) | ((uint)f2b(o1) << 16);
        *(uint*)((ushort*)outp + row * D_ + lane * 2) = packed;
    } else {
        float2 ov; ov.x = o0; ov.y = o1;
        *(float2*)((float*)outp + row * D_ + lane * 2) = ov;
    }
}

// ---------------------------------------------------------------------------
// MFMA bf16 GEMM: out[M,N] = A[M,K](bf16) @ Wt[N,K](bf16)^T + bias (+gelu)(+res)
// BM=128, BN=64, BK=128, 256 threads (4 waves 2x2), wave tile 64x32 (4x2 frags).
// LDS XOR-swizzle: elem_idx ^ ((row&7)<<3)  (i.e. byte ^ ((row&7)<<4)).
template <bool OBF, bool GELU, bool RESID>
__global__ __launch_bounds__(256) void gemm_k2(const ushort* __restrict__ A,
                                               const ushort* __restrict__ Wt,
                                               const float* __restrict__ bias,
                                               const float* res,
                                               void* outp,
                                               int K, int N) {
    __shared__ ushort Al[128 * 128];  // 32 KB
    __shared__ ushort Bl[64 * 128];   // 16 KB
    const int tid = threadIdx.x;
    const int lane = tid & 63, wid = tid >> 6;
    const int lr = lane & 15, lh = lane >> 4;       // frag row/col, k-group
    const int wr = wid >> 1, wc = wid & 1;
    const long row0 = (long)blockIdx.x * 128;
    const int  col0 = blockIdx.y * 64;

    f32x4 acc[4][2];
    #pragma unroll
    for (int i = 0; i < 4; ++i)
        #pragma unroll
        for (int j = 0; j < 2; ++j) { f32x4 z = {0.f, 0.f, 0.f, 0.f}; acc[i][j] = z; }

    for (int k0 = 0; k0 < K; k0 += 128) {
        // stage A: 128 rows x 16 slots(16B)
        #pragma unroll
        for (int i = 0; i < 8; ++i) {
            int idx = i * 256 + tid;
            int r = idx >> 4, s = idx & 15;
            uint4 d = *(const uint4*)(A + (row0 + r) * (long)K + k0 + s * 8);
            int w = (r * 128 + s * 8) ^ ((r & 7) << 3);
            *(uint4*)&Al[w] = d;
        }
        // stage B: 64 rows x 16 slots
        #pragma unroll
        for (int i = 0; i < 4; ++i) {
            int idx = i * 256 + tid;
            int r = idx >> 4, s = idx & 15;
            uint4 d = *(const uint4*)(Wt + (col0 + r) * (long)K + k0 + s * 8);
            int w = (r * 128 + s * 8) ^ ((r & 7) << 3);
            *(uint4*)&Bl[w] = d;
        }
        __syncthreads();
        #pragma unroll
        for (int ks = 0; ks < 4; ++ks) {
            bf16x8 af[4], bfr[2];
            #pragma unroll
            for (int fi = 0; fi < 4; ++fi) {
                int r = (wr << 6) + (fi << 4) + lr;
                int w = (r * 128 + ((ks << 2) + lh) * 8) ^ ((r & 7) << 3);
                af[fi] = *(const bf16x8*)&Al[w];
            }
            #pragma unroll
            for (int fj = 0; fj < 2; ++fj) {
                int c = (wc << 5) + (fj << 4) + lr;
                int w = (c * 128 + ((ks << 2) + lh) * 8) ^ ((c & 7) << 3);
                bfr[fj] = *(const bf16x8*)&Bl[w];
            }
            #pragma unroll
            for (int fi = 0; fi < 4; ++fi)
                #pragma unroll
                for (int fj = 0; fj < 2; ++fj)
                    acc[fi][fj] = __builtin_amdgcn_mfma_f32_16x16x32_bf16(
                        af[fi], bfr[fj], acc[fi][fj], 0, 0, 0);
        }
        __syncthreads();
    }

    // Epilogue. C/D: col = lane&15, row = (lane>>4)*4 + reg  [m89-verified]
    #pragma unroll
    for (int fi = 0; fi < 4; ++fi) {
        #pragma unroll
        for (int fj = 0; fj < 2; ++fj) {
            int col = col0 + (wc << 5) + (fj << 4) + lr;
            float bv = bias[col];
            #pragma unroll
            for (int rg = 0; rg < 4; ++rg) {
                long row = row0 + (wr << 6) + (fi << 4) + lh * 4 + rg;
                float val = acc[fi][fj][rg] + bv;
                if (GELU) val = 0.5f * val * (1.0f + erff(val * 0.70710678f));
                if (RESID) val += res[row * (long)N + col];
                if (OBF) ((ushort*)outp)[row * (long)N + col] = f2b(val);
                else     ((float*)outp)[row * (long)N + col] = val;
            }
        }
    }
}

// ---------------------------------------------------------------------------
// Attention: one block per batch b, 512 threads. All-head K/V in LDS (bf16).
// Thread = (head h = tid&7, base row i0 = tid>>3); 3 q-rows per thread.
// Single-pass softmax, no max subtraction (scores are O(1)), bitmask in regs.
__global__ __launch_bounds__(512) void attn2_k(const ushort* __restrict__ qkv,
                                               const uint* __restrict__ mb,
                                               ushort* __restrict__ o) {
    __shared__ ushort ks[S_ * 128];  // 47.5 KB
    __shared__ ushort vs[S_ * 128];
    const int b = blockIdx.x, tid = threadIdx.x;
    const long base = (long)b * S_ * 384;

    for (int idx = tid; idx < S_ * 16; idx += 512) {
        int r = idx >> 4, s = idx & 15;
        *(uint4*)&ks[r * 128 + s * 8] = *(const uint4*)(qkv + base + (long)r * 384 + 128 + s * 8);
        *(uint4*)&vs[r * 128 + s * 8] = *(const uint4*)(qkv + base + (long)r * 384 + 256 + s * 8);
    }
    __syncthreads();

    const int h = tid & 7, i0 = tid >> 3;
    const int r0 = i0, r1 = i0 + 64, r2 = i0 + 128;
    const bool v2 = (r2 < S_);

    float q0[16], q1[16], q2[16];
    unpack8(*(const uint4*)(qkv + base + (long)r0 * 384 + h * 16), q0);
    unpack8(*(const uint4*)(qkv + base + (long)r0 * 384 + h * 16 + 8), q0 + 8);
    unpack8(*(const uint4*)(qkv + base + (long)r1 * 384 + h * 16), q1);
    unpack8(*(const uint4*)(qkv + base + (long)r1 * 384 + h * 16 + 8), q1 + 8);
    if (v2) {
        unpack8(*(const uint4*)(qkv + base + (long)r2 * 384 + h * 16), q2);
        unpack8(*(const uint4*)(qkv + base + (long)r2 * 384 + h * 16 + 8), q2 + 8);
    } else {
        #pragma unroll
        for (int d = 0; d < 16; ++d) q2[d] = 0.f;
    }

    uint m0[6], m1[6], m2[6];
    #pragma unroll
    for (int w = 0; w < 6; ++w) {
        m0[w] = mb[r0 * 8 + w];
        m1[w] = mb[r1 * 8 + w];
        m2[w] = v2 ? mb[r2 * 8 + w] : 0u;
    }

    float l0 = 0.f, l1 = 0.f, l2 = 0.f;
    float a0[16] = {}, a1[16] = {}, a2[16] = {};

    for (int j = 0; j < S_; ++j) {
        float kf[16];
        unpack8(*(const uint4*)&ks[j * 128 + h * 16], kf);
        unpack8(*(const uint4*)&ks[j * 128 + h * 16 + 8], kf + 8);
        float s0 = 0.f, s1 = 0.f, s2 = 0.f;
        #pragma unroll
        for (int d = 0; d < 16; ++d) {
            s0 = fmaf(q0[d], kf[d], s0);
            s1 = fmaf(q1[d], kf[d], s1);
            s2 = fmaf(q2[d], kf[d], s2);
        }
        uint w = j >> 5, bit = j & 31;
        float p0 = ((m0[w] >> bit) & 1u) ? __expf(s0 * 0.25f) : 0.f;
        float p1 = ((m1[w] >> bit) & 1u) ? __expf(s1 * 0.25f) : 0.f;
        float p2 = ((m2[w] >> bit) & 1u) ? __expf(s2 * 0.25f) : 0.f;
        l0 += p0; l1 += p1; l2 += p2;
        float vf[16];
        unpack8(*(const uint4*)&vs[j * 128 + h * 16], vf);
        unpack8(*(const uint4*)&vs[j * 128 + h * 16 + 8], vf + 8);
        #pragma unroll
        for (int d = 0; d < 16; ++d) {
            a0[d] = fmaf(p0, vf[d], a0[d]);
            a1[d] = fmaf(p1, vf[d], a1[d]);
            a2[d] = fmaf(p2, vf[d], a2[d]);
        }
    }

    const long ob = (long)b * S_ * 128;
    float inv0 = 1.0f / l0, inv1 = 1.0f / l1;
    uint pw[8];
    #pragma unroll
    for (int d = 0; d < 8; ++d)
        pw[d] = (uint)f2b(a0[2*d] * inv0) | ((uint)f2b(a0[2*d+1] * inv0) << 16);
    { uint4 u; u.x = pw[0]; u.y = pw[1]; u.z = pw[2]; u.w = pw[3];
      *(uint4*)&o[ob + (long)r0 * 128 + h * 16] = u;
      u.x = pw[4]; u.y = pw[5]; u.z = pw[6]; u.w = pw[7];
      *(uint4*)&o[ob + (long)r0 * 128 + h * 16 + 8] = u; }
    #pragma unroll
    for (int d = 0; d < 8; ++d)
        pw[d] = (uint)f2b(a1[2*d] * inv1) | ((uint)f2b(a1[2*d+1] * inv1) << 16);
    { uint4 u; u.x = pw[0]; u.y = pw[1]; u.z = pw[2]; u.w = pw[3];
      *(uint4*)&o[ob + (long)r1 * 128 + h * 16] = u;
      u.x = pw[4]; u.y = pw[5]; u.z = pw[6]; u.w = pw[7];
      *(uint4*)&o[ob + (long)r1 * 128 + h * 16 + 8] = u; }
    if (v2) {
        float inv2 = 1.0f / l2;
        #pragma unroll
        for (int d = 0; d < 8; ++d)
            pw[d] = (uint)f2b(a2[2*d] * inv2) | ((uint)f2b(a2[2*d+1] * inv2) << 16);
        uint4 u; u.x = pw[0]; u.y = pw[1]; u.z = pw[2]; u.w = pw[3];
        *(uint4*)&o[ob + (long)r2 * 128 + h * 16] = u;
        u.x = pw[4]; u.y = pw[5]; u.z = pw[6]; u.w = pw[7];
        *(uint4*)&o[ob + (long)r2 * 128 + h * 16 + 8] = u;
    }
}

// ---------------------------------------------------------------------------
__global__ __launch_bounds__(256) void fin_k(const float* __restrict__ x,
                                             const float* __restrict__ g,
                                             const float* __restrict__ bta,
                                             const float* __restrict__ fw,
                                             const float* __restrict__ fb,
                                             float* __restrict__ t) {
    int wave = threadIdx.x >> 6;
    int lane = threadIdx.x & 63;
    long row = (long)blockIdx.x * 4 + wave;
    const float* r = x + row * D_;
    float2 v = *(const float2*)(r + lane * 2);
    float sum = v.x + v.y;
    float sq  = v.x * v.x + v.y * v.y;
    #pragma unroll
    for (int o = 32; o; o >>= 1) { sum += __shfl_xor(sum, o); sq += __shfl_xor(sq, o); }
    float mean = sum * (1.0f / D_);
    float var  = sq * (1.0f / D_) - mean * mean;
    float inv  = rsqrtf(var + 1e-5f);
    float2 gv = *(const float2*)(g + lane * 2);
    float2 bv = *(const float2*)(bta + lane * 2);
    float y0 = gv.x * (v.x - mean) * inv + bv.x;
    float y1 = gv.y * (v.y - mean) * inv + bv.y;
    float part = y0 * fw[lane * 2] + y1 * fw[lane * 2 + 1];
    #pragma unroll
    for (int o = 32; o; o >>= 1) part += __shfl_xor(part, o);
    if (lane == 0) t[row] = part + fb[0];
}

__global__ __launch_bounds__(128) void outgemm_k(const float* __restrict__ t,
                                                 const float* __restrict__ ow,
                                                 const float* __restrict__ ob,
                                                 float* __restrict__ out) {
    __shared__ float ts[S_];
    int b = blockIdx.x, tid = threadIdx.x;
    for (int i = tid; i < S_; i += 128) ts[i] = t[(long)b * S_ + i];
    __syncthreads();
    if (tid < CN_) {
        float acc = ob[tid];
        for (int s = 0; s < S_; ++s) acc = fmaf(ts[s], ow[s * CN_ + tid], acc);
        out[(long)b * CN_ + tid] = acc;
    }
}

// ---------------------------------------------------------------------------
extern "C" void kernel_launch(void* const* d_in, const int* in_sizes, int n_in,
                              void* d_out, int out_size, void* d_ws, size_t ws_size,
                              hipStream_t stream) {
    const float* mag  = (const float*)d_in[0];
    const float* syn  = (const float*)d_in[1];
    const int*   pc   = (const int*)  d_in[2];
    const float* se   = (const float*)d_in[3];
    const float* Wq   = (const float*)d_in[4];
    const float* bq   = (const float*)d_in[5];
    const float* Wk   = (const float*)d_in[6];
    const float* bk   = (const float*)d_in[7];
    const float* Wv   = (const float*)d_in[8];
    const float* bv   = (const float*)d_in[9];
    const float* Wo   = (const float*)d_in[10];
    const float* bo   = (const float*)d_in[11];
    const float* W1   = (const float*)d_in[12];
    const float* b1   = (const float*)d_in[13];
    const float* W2   = (const float*)d_in[14];
    const float* b2   = (const float*)d_in[15];
    const float* ln1g = (const float*)d_in[16];
    const float* ln1b = (const float*)d_in[17];
    const float* ln2g = (const float*)d_in[18];
    const float* ln2b = (const float*)d_in[19];
    const float* encg = (const float*)d_in[20];
    const float* encb = (const float*)d_in[21];
    const float* n2g  = (const float*)d_in[22];
    const float* n2b  = (const float*)d_in[23];
    const float* finw = (const float*)d_in[24];
    const float* finb = (const float*)d_in[25];
    const float* outw = (const float*)d_in[26];
    const float* outb = (const float*)d_in[27];
    float* out = (float*)d_out;

    // Workspace layout (bytes), total ~170.4 MiB:
    char* p = (char*)d_ws;
    float*  x     = (float*) p;                      // 49,807,360  x f32 [MR][128]
    ushort* h     = (ushort*)(p + 49807360);         // 24,903,680  h bf16 (o aliases)
    ushort* qkv   = (ushort*)(p + 74711040);         // 99,614,720  qkv bf16 [MR][384] / ff1 [MR][512]
    ushort* Wqkvt = (ushort*)(p + 174325760);        //    983,040  [10][384][128]
    ushort* Wot   = (ushort*)(p + 175308800);        //    327,680  [10][128][128]
    ushort* W1t   = (ushort*)(p + 175636480);        //  1,310,720  [10][512][128]
    ushort* W2t   = (ushort*)(p + 176947200);        //  1,310,720  [10][128][512]
    float*  bqkv  = (float*) (p + 178257920);        //     15,360  [10][384]
    uint*   mb    = (uint*)  (p + 178273280);        //      6,080  [190][8]
    float*  t     = (float*) (p + 178279360);        //    389,120  [MR]
    ushort* o     = h;
    ushort* ff1   = qkv;

    mbits_k<<<6, 256, 0, stream>>>(pc, mb);
    embed_k<<<(int)(((long)MR_ * D_ + 255) / 256), 256, 0, stream>>>(mag, syn, se, x);
    wtr_qkv_k<<<1920, 256, 0, stream>>>(Wq, Wk, Wv, Wqkvt);
    wtr_k<<<640, 256, 0, stream>>>(Wo, Wot, 128, 128);
    wtr_k<<<2560, 256, 0, stream>>>(W1, W1t, 128, 512);
    wtr_k<<<2560, 256, 0, stream>>>(W2, W2t, 512, 128);
    bcat_k<<<15, 256, 0, stream>>>(bq, bk, bv, bqkv);

    for (int i = 0; i < NDEC_; ++i) {
        ln_k<true><<<MR_ / 4, 256, 0, stream>>>(x, ln1g + i * D_, ln1b + i * D_, h);
        gemm_k2<true, false, false><<<dim3(760, 6), 256, 0, stream>>>(
            h, Wqkvt + (long)i * 49152, bqkv + i * 384, nullptr, qkv, 128, 384);
        attn2_k<<<B_, 512, 0, stream>>>(qkv, mb, o);
        gemm_k2<false, false, true><<<dim3(760, 2), 256, 0, stream>>>(
            o, Wot + (long)i * 16384, bo + i * 128, x, x, 128, 128);
        ln_k<true><<<MR_ / 4, 256, 0, stream>>>(x, ln2g + i * D_, ln2b + i * D_, h);
        gemm_k2<true, true, false><<<dim3(760, 8), 256, 0, stream>>>(
            h, W1t + (long)i * 65536, b1 + i * 512, nullptr, ff1, 128, 512);
        gemm_k2<false, false, true><<<dim3(760, 2), 256, 0, stream>>>(
            ff1, W2t + (long)i * 65536, b2 + i * 128, x, x, 512, 128);
        if (i == 4) {
            ln_k<false><<<MR_ / 4, 256, 0, stream>>>(x, n2g, n2b, x);
        }
    }

    fin_k<<<MR_ / 4, 256, 0, stream>>>(x, encg, encb, finw, finb, t);
    outgemm_k<<<B_, 128, 0, stream>>>(t, outw, outb, out);
}

// Round 4
// 3199.603 us; speedup vs baseline: 3.5575x; 1.4319x over previous
//
#include <hip/hip_runtime.h>
#include <math.h>

typedef unsigned int uint;
typedef unsigned short ushort;

// Problem constants
constexpr int B_    = 512;
constexpr int S_    = 190;   // CODE_N + PC_ROWS
constexpr int D_    = 128;
constexpr int DFF_  = 512;
constexpr int NDEC_ = 10;
constexpr int CN_   = 127;
constexpr int PCR_  = 63;
constexpr int MR_   = B_ * S_;  // 97280 = 760*128

typedef __attribute__((ext_vector_type(4))) short bf16x4;
typedef __attribute__((ext_vector_type(8))) short bf16x8;
typedef __attribute__((ext_vector_type(4))) float f32x4;

// bf16 helpers
__device__ __forceinline__ float blo(uint w) { return __uint_as_float(w << 16); }
__device__ __forceinline__ float bhi(uint w) { return __uint_as_float(w & 0xffff0000u); }
__device__ __forceinline__ ushort f2b(float f) {
    uint x = __float_as_uint(f);
    uint r = x + 0x7fffu + ((x >> 16) & 1u);
    return (ushort)(r >> 16);
}

// ---------------------------------------------------------------------------
// Mask bitmask: mb[i][w] bit b set = position j=w*32+b is ALLOWED.
__device__ bool allow_f(int i, int j, const int* pc) {
    if (i < CN_ && j < CN_) {
        if (i == j) return true;
        for (int m = 0; m < PCR_; ++m)
            if (pc[m * CN_ + i] > 0 && pc[m * CN_ + j] > 0) return true;
        return false;
    } else if (i < CN_) {
        return pc[(j - CN_) * CN_ + i] > 0;
    } else if (j < CN_) {
        return pc[(i - CN_) * CN_ + j] > 0;
    }
    return i == j;
}

__global__ void mbits_k(const int* __restrict__ pc, uint* __restrict__ mb) {
    int idx = blockIdx.x * 256 + threadIdx.x;
    if (idx >= S_ * 8) return;
    int i = idx >> 3, w = idx & 7;
    uint word = 0;
    if (w < 6) {
        for (int b = 0; b < 32; ++b) {
            int j = w * 32 + b;
            if (j < S_ && allow_f(i, j, pc)) word |= (1u << b);
        }
    }
    mb[idx] = word;
}

// ---------------------------------------------------------------------------
__global__ void embed_k(const float* __restrict__ mag, const float* __restrict__ syn,
                        const float* __restrict__ se, float* __restrict__ x) {
    long idx = (long)blockIdx.x * blockDim.x + threadIdx.x;
    if (idx >= (long)MR_ * D_) return;
    int d  = (int)(idx & (D_ - 1));
    long bs = idx >> 7;
    int s = (int)(bs % S_);
    int b = (int)(bs / S_);
    float e = (s < CN_) ? mag[b * CN_ + s] : syn[b * PCR_ + (s - CN_)];
    x[idx] = se[s * D_ + d] * e;
}

// ---------------------------------------------------------------------------
// Weight transpose to bf16 [L][N][K]
__global__ void wtr_k(const float* __restrict__ src, ushort* __restrict__ dst,
                      int K, int N) {
    int idx = blockIdx.x * 256 + threadIdx.x;
    int KN = K * N;
    int l = idx / KN, rem = idx % KN;
    int n = rem / K, k = rem % K;
    dst[idx] = f2b(src[(long)l * KN + (long)k * N + n]);
}

// Fused QKV weight transpose: dst [10][384][128]
__global__ void wtr_qkv_k(const float* __restrict__ Wq, const float* __restrict__ Wk,
                          const float* __restrict__ Wv, ushort* __restrict__ dst) {
    int idx = blockIdx.x * 256 + threadIdx.x;   // 491520
    int l = idx / (384 * 128);
    int rem = idx % (384 * 128);
    int n = rem >> 7, k = rem & 127;
    const float* src = (n < 128) ? Wq : (n < 256) ? Wk : Wv;
    dst[idx] = f2b(src[l * 16384 + k * 128 + (n & 127)]);
}

__global__ void bcat_k(const float* __restrict__ bq, const float* __restrict__ bk,
                       const float* __restrict__ bv, float* __restrict__ dst) {
    int idx = blockIdx.x * 256 + threadIdx.x;   // 3840
    int l = idx / 384, n = idx % 384;
    const float* s = (n < 128) ? bq : (n < 256) ? bk : bv;
    dst[idx] = s[l * 128 + (n & 127)];
}

// ---------------------------------------------------------------------------
// LayerNorm: one wave per 128-row; 4 rows/block. OBF: bf16 out.
template <bool OBF>
__global__ __launch_bounds__(256) void ln_k(const float* __restrict__ in,
                                            const float* __restrict__ g,
                                            const float* __restrict__ bta,
                                            void* outp) {
    int wave = threadIdx.x >> 6;
    int lane = threadIdx.x & 63;
    long row = (long)blockIdx.x * 4 + wave;
    const float* r = in + row * D_;
    float2 v = *(const float2*)(r + lane * 2);
    float sum = v.x + v.y;
    float sq  = v.x * v.x + v.y * v.y;
    #pragma unroll
    for (int o = 32; o; o >>= 1) { sum += __shfl_xor(sum, o); sq += __shfl_xor(sq, o); }
    float mean = sum * (1.0f / D_);
    float var  = sq * (1.0f / D_) - mean * mean;
    float inv  = rsqrtf(var + 1e-5f);
    float2 gv = *(const float2*)(g + lane * 2);
    float2 bv = *(const float2*)(bta + lane * 2);
    float o0 = gv.x * (v.x - mean) * inv + bv.x;
    float o1 = gv.y * (v.y - mean) * inv + bv.y;
    if (OBF) {
        uint packed = (uint)f2b(o0) | ((uint)f2b(o1) << 16);
        *(uint*)((ushort*)outp + row * D_ + lane * 2) = packed;
    } else {
        float2 ov; ov.x = o0; ov.y = o1;
        *(float2*)((float*)outp + row * D_ + lane * 2) = ov;
    }
}

// ---------------------------------------------------------------------------
// MFMA bf16 GEMM (unchanged from round 3, proven).
template <bool OBF, bool GELU, bool RESID>
__global__ __launch_bounds__(256) void gemm_k2(const ushort* __restrict__ A,
                                               const ushort* __restrict__ Wt,
                                               const float* __restrict__ bias,
                                               const float* res,
                                               void* outp,
                                               int K, int N) {
    __shared__ ushort Al[128 * 128];
    __shared__ ushort Bl[64 * 128];
    const int tid = threadIdx.x;
    const int lane = tid & 63, wid = tid >> 6;
    const int lr = lane & 15, lh = lane >> 4;
    const int wr = wid >> 1, wc = wid & 1;
    const long row0 = (long)blockIdx.x * 128;
    const int  col0 = blockIdx.y * 64;

    f32x4 acc[4][2];
    #pragma unroll
    for (int i = 0; i < 4; ++i)
        #pragma unroll
        for (int j = 0; j < 2; ++j) { f32x4 z = {0.f, 0.f, 0.f, 0.f}; acc[i][j] = z; }

    for (int k0 = 0; k0 < K; k0 += 128) {
        #pragma unroll
        for (int i = 0; i < 8; ++i) {
            int idx = i * 256 + tid;
            int r = idx >> 4, s = idx & 15;
            uint4 d = *(const uint4*)(A + (row0 + r) * (long)K + k0 + s * 8);
            int w = (r * 128 + s * 8) ^ ((r & 7) << 3);
            *(uint4*)&Al[w] = d;
        }
        #pragma unroll
        for (int i = 0; i < 4; ++i) {
            int idx = i * 256 + tid;
            int r = idx >> 4, s = idx & 15;
            uint4 d = *(const uint4*)(Wt + (col0 + r) * (long)K + k0 + s * 8);
            int w = (r * 128 + s * 8) ^ ((r & 7) << 3);
            *(uint4*)&Bl[w] = d;
        }
        __syncthreads();
        #pragma unroll
        for (int ks = 0; ks < 4; ++ks) {
            bf16x8 af[4], bfr[2];
            #pragma unroll
            for (int fi = 0; fi < 4; ++fi) {
                int r = (wr << 6) + (fi << 4) + lr;
                int w = (r * 128 + ((ks << 2) + lh) * 8) ^ ((r & 7) << 3);
                af[fi] = *(const bf16x8*)&Al[w];
            }
            #pragma unroll
            for (int fj = 0; fj < 2; ++fj) {
                int c = (wc << 5) + (fj << 4) + lr;
                int w = (c * 128 + ((ks << 2) + lh) * 8) ^ ((c & 7) << 3);
                bfr[fj] = *(const bf16x8*)&Bl[w];
            }
            #pragma unroll
            for (int fi = 0; fi < 4; ++fi)
                #pragma unroll
                for (int fj = 0; fj < 2; ++fj)
                    acc[fi][fj] = __builtin_amdgcn_mfma_f32_16x16x32_bf16(
                        af[fi], bfr[fj], acc[fi][fj], 0, 0, 0);
        }
        __syncthreads();
    }

    #pragma unroll
    for (int fi = 0; fi < 4; ++fi) {
        #pragma unroll
        for (int fj = 0; fj < 2; ++fj) {
            int col = col0 + (wc << 5) + (fj << 4) + lr;
            float bv = bias[col];
            #pragma unroll
            for (int rg = 0; rg < 4; ++rg) {
                long row = row0 + (wr << 6) + (fi << 4) + lh * 4 + rg;
                float val = acc[fi][fj][rg] + bv;
                if (GELU) val = 0.5f * val * (1.0f + erff(val * 0.70710678f));
                if (RESID) val += res[row * (long)N + col];
                if (OBF) ((ushort*)outp)[row * (long)N + col] = f2b(val);
                else     ((float*)outp)[row * (long)N + col] = val;
            }
        }
    }
}

// ---------------------------------------------------------------------------
// MFMA attention. Block = batch b (512 blocks x 512 threads); wave = head.
// T = K·Q^T via mfma_f32_16x16x32_bf16 (K-side zero-padded: dk=16 in K=32).
// T's C/D layout (col=q, row=j) IS the A-frag layout for K=16 PV MFMA, so
// softmax is lane-local; P normalized pre-PV; PV via v_mfma_f32_16x16x16_bf16
// (inline asm, ISA-doc'd) with s_nop hazard guards.
// LDS: K,V rows XOR-swizzled (elem c -> c ^ ((s&7)<<3)).
__device__ __forceinline__ int lds_e(int s, int c) {
    return s * 128 + (c ^ ((s & 7) << 3));
}

__global__ __launch_bounds__(512) void attn3_k(const ushort* __restrict__ qkv,
                                               const uint* __restrict__ mb,
                                               ushort* __restrict__ o) {
    __shared__ ushort ks[S_ * 128];  // 47.5 KB
    __shared__ ushort vs[S_ * 128];  // 47.5 KB
    const int b = blockIdx.x, tid = threadIdx.x;
    const long base = (long)b * S_ * 384;

    for (int idx = tid; idx < S_ * 16; idx += 512) {
        int r = idx >> 4, sl = idx & 15;
        uint4 uk = *(const uint4*)(qkv + base + (long)r * 384 + 128 + sl * 8);
        uint4 uv = *(const uint4*)(qkv + base + (long)r * 384 + 256 + sl * 8);
        int w = lds_e(r, sl * 8);
        *(uint4*)&ks[w] = uk;
        *(uint4*)&vs[w] = uv;
    }
    __syncthreads();

    const int h = tid >> 6;            // wave = head
    const int lane = tid & 63;
    const int lr = lane & 15, lh = lane >> 4;
    const int lh2 = lh & 1;

    // K-frags: lane holds K[jt*16+lr][d = lh2*8 + e]; zero for lh>=2 (pad K 16->32).
    bf16x8 kf[12];
    #pragma unroll
    for (int jt = 0; jt < 12; ++jt) {
        int j = jt * 16 + lr; if (j > 189) j = 189;
        bf16x8 v8 = *(const bf16x8*)&ks[lds_e(j, h * 16 + lh2 * 8)];
        if (lh >= 2) { bf16x8 z = {0,0,0,0,0,0,0,0}; v8 = z; }
        kf[jt] = v8;
    }
    // V-frags: lane holds V[jt*16 + 4*lh + e][d = h*16 + lr], e=0..3.
    bf16x4 vf[12];
    #pragma unroll
    for (int jt = 0; jt < 12; ++jt) {
        int j0 = jt * 16 + lh * 4;
        int c = h * 16 + lr;
        int ja = j0 + 0 > 189 ? 189 : j0 + 0;
        int jb = j0 + 1 > 189 ? 189 : j0 + 1;
        int jc = j0 + 2 > 189 ? 189 : j0 + 2;
        int jd = j0 + 3 > 189 ? 189 : j0 + 3;
        bf16x4 v4;
        v4[0] = (short)vs[lds_e(ja, c)];
        v4[1] = (short)vs[lds_e(jb, c)];
        v4[2] = (short)vs[lds_e(jc, c)];
        v4[3] = (short)vs[lds_e(jd, c)];
        vf[jt] = v4;
    }

    // Q-frag for q-tile 0 (B-operand: col=lr=q, k=lh2*8+e=d; lh>=2 garbage OK).
    int sq = lr; // qt=0
    bf16x8 qf = *(const bf16x8*)(qkv + base + (long)sq * 384 + h * 16 + lh2 * 8);

    for (int qt = 0; qt < 12; ++qt) {
        // Scores^T: T[jt] covers j in [jt*16, jt*16+16), q in [qt*16, qt*16+16).
        f32x4 T[12];
        f32x4 zero = {0.f, 0.f, 0.f, 0.f};
        #pragma unroll
        for (int jt = 0; jt < 12; ++jt)
            T[jt] = __builtin_amdgcn_mfma_f32_16x16x32_bf16(kf[jt], qf, zero, 0, 0, 0);

        // prefetch next Q-frag
        {
            int sn = (qt + 1) * 16 + lr; if (sn > 189) sn = 189;
            qf = *(const bf16x8*)(qkv + base + (long)sn * 384 + h * 16 + lh2 * 8);
        }

        // masks for this lane's q row
        int qc = qt * 16 + lr; if (qc > 189) qc = 189;
        uint mw[6];
        #pragma unroll
        for (int w = 0; w < 6; ++w) mw[w] = mb[qc * 8 + w];

        // lane-local masked exp + column sum (j runs over lanes lh and regs)
        float p[12][4];
        float lsum = 0.f;
        #pragma unroll
        for (int jt = 0; jt < 12; ++jt) {
            uint word = mw[jt >> 1];
            #pragma unroll
            for (int r = 0; r < 4; ++r) {
                int bit = ((jt & 1) << 4) + 4 * lh + r;
                float e = __expf(T[jt][r] * 0.25f);
                float pv = ((word >> bit) & 1u) ? e : 0.f;
                p[jt][r] = pv;
                lsum += pv;
            }
        }
        lsum += __shfl_xor(lsum, 16);
        lsum += __shfl_xor(lsum, 32);
        float inv = 1.0f / lsum;

        // PV: acc[q][d] += P_frag[jt] x V_frag[jt]  (K=16 MFMA, C-chained)
        f32x4 acc = {0.f, 0.f, 0.f, 0.f};
        #pragma unroll
        for (int jt = 0; jt < 12; ++jt) {
            uint lo, hi;
            float a0 = p[jt][0] * inv, a1 = p[jt][1] * inv;
            float a2 = p[jt][2] * inv, a3 = p[jt][3] * inv;
            asm("v_cvt_pk_bf16_f32 %0, %1, %2" : "=v"(lo) : "v"(a0), "v"(a1));
            asm("v_cvt_pk_bf16_f32 %0, %1, %2" : "=v"(hi) : "v"(a2), "v"(a3));
            uint2 u; u.x = lo; u.y = hi;
            bf16x4 pf = *(bf16x4*)&u;
            // s_nop guards the VALU-write -> MFMA-read hazard window.
            asm("s_nop 1\n\tv_mfma_f32_16x16x16_bf16 %0, %1, %2, %0"
                : "+v"(acc) : "v"(pf), "v"(vf[jt]));
        }
        // MFMA-write -> VALU-read guard, tied into acc's dependency chain.
        asm volatile("s_nop 7\n\ts_nop 7" : "+v"(acc));

        // store: C/D col=lr=d, row=4*lh+r=q_local
        #pragma unroll
        for (int r = 0; r < 4; ++r) {
            int qg = qt * 16 + 4 * lh + r;
            if (qg < S_)
                o[((long)b * S_ + qg) * 128 + h * 16 + lr] = f2b(acc[r]);
        }
    }
}

// ---------------------------------------------------------------------------
__global__ __launch_bounds__(256) void fin_k(const float* __restrict__ x,
                                             const float* __restrict__ g,
                                             const float* __restrict__ bta,
                                             const float* __restrict__ fw,
                                             const float* __restrict__ fb,
                                             float* __restrict__ t) {
    int wave = threadIdx.x >> 6;
    int lane = threadIdx.x & 63;
    long row = (long)blockIdx.x * 4 + wave;
    const float* r = x + row * D_;
    float2 v = *(const float2*)(r + lane * 2);
    float sum = v.x + v.y;
    float sq  = v.x * v.x + v.y * v.y;
    #pragma unroll
    for (int o = 32; o; o >>= 1) { sum += __shfl_xor(sum, o); sq += __shfl_xor(sq, o); }
    float mean = sum * (1.0f / D_);
    float var  = sq * (1.0f / D_) - mean * mean;
    float inv  = rsqrtf(var + 1e-5f);
    float2 gv = *(const float2*)(g + lane * 2);
    float2 bv = *(const float2*)(bta + lane * 2);
    float y0 = gv.x * (v.x - mean) * inv + bv.x;
    float y1 = gv.y * (v.y - mean) * inv + bv.y;
    float part = y0 * fw[lane * 2] + y1 * fw[lane * 2 + 1];
    #pragma unroll
    for (int o = 32; o; o >>= 1) part += __shfl_xor(part, o);
    if (lane == 0) t[row] = part + fb[0];
}

__global__ __launch_bounds__(128) void outgemm_k(const float* __restrict__ t,
                                                 const float* __restrict__ ow,
                                                 const float* __restrict__ ob,
                                                 float* __restrict__ out) {
    __shared__ float ts[S_];
    int b = blockIdx.x, tid = threadIdx.x;
    for (int i = tid; i < S_; i += 128) ts[i] = t[(long)b * S_ + i];
    __syncthreads();
    if (tid < CN_) {
        float acc = ob[tid];
        for (int s = 0; s < S_; ++s) acc = fmaf(ts[s], ow[s * CN_ + tid], acc);
        out[(long)b * CN_ + tid] = acc;
    }
}

// ---------------------------------------------------------------------------
extern "C" void kernel_launch(void* const* d_in, const int* in_sizes, int n_in,
                              void* d_out, int out_size, void* d_ws, size_t ws_size,
                              hipStream_t stream) {
    const float* mag  = (const float*)d_in[0];
    const float* syn  = (const float*)d_in[1];
    const int*   pc   = (const int*)  d_in[2];
    const float* se   = (const float*)d_in[3];
    const float* Wq   = (const float*)d_in[4];
    const float* bq   = (const float*)d_in[5];
    const float* Wk   = (const float*)d_in[6];
    const float* bk   = (const float*)d_in[7];
    const float* Wv   = (const float*)d_in[8];
    const float* bv   = (const float*)d_in[9];
    const float* Wo   = (const float*)d_in[10];
    const float* bo   = (const float*)d_in[11];
    const float* W1   = (const float*)d_in[12];
    const float* b1   = (const float*)d_in[13];
    const float* W2   = (const float*)d_in[14];
    const float* b2   = (const float*)d_in[15];
    const float* ln1g = (const float*)d_in[16];
    const float* ln1b = (const float*)d_in[17];
    const float* ln2g = (const float*)d_in[18];
    const float* ln2b = (const float*)d_in[19];
    const float* encg = (const float*)d_in[20];
    const float* encb = (const float*)d_in[21];
    const float* n2g  = (const float*)d_in[22];
    const float* n2b  = (const float*)d_in[23];
    const float* finw = (const float*)d_in[24];
    const float* finb = (const float*)d_in[25];
    const float* outw = (const float*)d_in[26];
    const float* outb = (const float*)d_in[27];
    float* out = (float*)d_out;

    // Workspace layout (bytes), total ~170.4 MiB
    char* p = (char*)d_ws;
    float*  x     = (float*) p;                      // x f32 [MR][128]
    ushort* h     = (ushort*)(p + 49807360);         // h bf16 (o aliases)
    ushort* qkv   = (ushort*)(p + 74711040);         // qkv bf16 [MR][384] / ff1 [MR][512]
    ushort* Wqkvt = (ushort*)(p + 174325760);        // [10][384][128]
    ushort* Wot   = (ushort*)(p + 175308800);        // [10][128][128]
    ushort* W1t   = (ushort*)(p + 175636480);        // [10][512][128]
    ushort* W2t   = (ushort*)(p + 176947200);        // [10][128][512]
    float*  bqkv  = (float*) (p + 178257920);        // [10][384]
    uint*   mb    = (uint*)  (p + 178273280);        // [190][8]
    float*  t     = (float*) (p + 178279360);        // [MR]
    ushort* o     = h;
    ushort* ff1   = qkv;

    mbits_k<<<6, 256, 0, stream>>>(pc, mb);
    embed_k<<<(int)(((long)MR_ * D_ + 255) / 256), 256, 0, stream>>>(mag, syn, se, x);
    wtr_qkv_k<<<1920, 256, 0, stream>>>(Wq, Wk, Wv, Wqkvt);
    wtr_k<<<640, 256, 0, stream>>>(Wo, Wot, 128, 128);
    wtr_k<<<2560, 256, 0, stream>>>(W1, W1t, 128, 512);
    wtr_k<<<2560, 256, 0, stream>>>(W2, W2t, 512, 128);
    bcat_k<<<15, 256, 0, stream>>>(bq, bk, bv, bqkv);

    for (int i = 0; i < NDEC_; ++i) {
        ln_k<true><<<MR_ / 4, 256, 0, stream>>>(x, ln1g + i * D_, ln1b + i * D_, h);
        gemm_k2<true, false, false><<<dim3(760, 6), 256, 0, stream>>>(
            h, Wqkvt + (long)i * 49152, bqkv + i * 384, nullptr, qkv, 128, 384);
        attn3_k<<<B_, 512, 0, stream>>>(qkv, mb, o);
        gemm_k2<false, false, true><<<dim3(760, 2), 256, 0, stream>>>(
            o, Wot + (long)i * 16384, bo + i * 128, x, x, 128, 128);
        ln_k<true><<<MR_ / 4, 256, 0, stream>>>(x, ln2g + i * D_, ln2b + i * D_, h);
        gemm_k2<true, true, false><<<dim3(760, 8), 256, 0, stream>>>(
            h, W1t + (long)i * 65536, b1 + i * 512, nullptr, ff1, 128, 512);
        gemm_k2<false, false, true><<<dim3(760, 2), 256, 0, stream>>>(
            ff1, W2t + (long)i * 65536, b2 + i * 128, x, x, 512, 128);
        if (i == 4) {
            ln_k<false><<<MR_ / 4, 256, 0, stream>>>(x, n2g, n2b, x);
        }
    }

    fin_k<<<MR_ / 4, 256, 0, stream>>>(x, encg, encb, finw, finb, t);
    outgemm_k<<<B_, 128, 0, stream>>>(t, outw, outb, out);
}

// Round 5
// 2684.936 us; speedup vs baseline: 4.2394x; 1.1917x over previous
//
#include <hip/hip_runtime.h>
#include <math.h>

typedef unsigned int uint;
typedef unsigned short ushort;
typedef unsigned long long u64;

// Problem constants
constexpr int B_    = 512;
constexpr int S_    = 190;   // CODE_N + PC_ROWS
constexpr int D_    = 128;
constexpr int DFF_  = 512;
constexpr int NDEC_ = 10;
constexpr int CN_   = 127;
constexpr int PCR_  = 63;
constexpr int MR_   = B_ * S_;  // 97280 = 760*128

typedef __attribute__((ext_vector_type(4))) short bf16x4;
typedef __attribute__((ext_vector_type(8))) short bf16x8;
typedef __attribute__((ext_vector_type(4))) float f32x4;

// bf16 helpers
__device__ __forceinline__ float blo(uint w) { return __uint_as_float(w << 16); }
__device__ __forceinline__ float bhi(uint w) { return __uint_as_float(w & 0xffff0000u); }
__device__ __forceinline__ ushort f2b(float f) {
    uint x = __float_as_uint(f);
    uint r = x + 0x7fffu + ((x >> 16) & 1u);
    return (ushort)(r >> 16);
}

// ---------------------------------------------------------------------------
// Mask bitmask via per-variable check-membership bitsets.
// chk[i] = 63-bit set of checks containing variable i.
// allow(i,j): i,j<127: i==j || chk[i]&chk[j]; i<127,j>=127: chk[i]>>(j-127)&1;
//             i>=127,j<127: chk[j]>>(i-127)&1; else i==j.
__global__ __launch_bounds__(256) void mbits2_k(const int* __restrict__ pc,
                                                uint* __restrict__ mb) {
    __shared__ u64 chk[CN_];
    int tid = threadIdx.x;
    if (tid < CN_) {
        u64 m = 0;
        for (int r = 0; r < PCR_; ++r)
            if (pc[r * CN_ + tid] > 0) m |= (1ull << r);
        chk[tid] = m;
    }
    __syncthreads();
    for (int idx = tid; idx < S_ * 8; idx += 256) {
        int i = idx >> 3, w = idx & 7;
        uint word = 0;
        if (w < 6) {
            for (int b = 0; b < 32; ++b) {
                int j = w * 32 + b;
                if (j >= S_) break;
                bool al;
                if (i < CN_ && j < CN_)      al = (i == j) || ((chk[i] & chk[j]) != 0ull);
                else if (i < CN_)            al = (chk[i] >> (j - CN_)) & 1ull;
                else if (j < CN_)            al = (chk[j] >> (i - CN_)) & 1ull;
                else                         al = (i == j);
                if (al) word |= (1u << b);
            }
        }
        mb[idx] = word;
    }
}

// ---------------------------------------------------------------------------
__global__ void embed_k(const float* __restrict__ mag, const float* __restrict__ syn,
                        const float* __restrict__ se, float* __restrict__ x) {
    long idx = (long)blockIdx.x * blockDim.x + threadIdx.x;
    if (idx >= (long)MR_ * D_) return;
    int d  = (int)(idx & (D_ - 1));
    long bs = idx >> 7;
    int s = (int)(bs % S_);
    int b = (int)(bs / S_);
    float e = (s < CN_) ? mag[b * CN_ + s] : syn[b * PCR_ + (s - CN_)];
    x[idx] = se[s * D_ + d] * e;
}

// ---------------------------------------------------------------------------
// Weight transpose to bf16 [L][N][K]
__global__ void wtr_k(const float* __restrict__ src, ushort* __restrict__ dst,
                      int K, int N) {
    int idx = blockIdx.x * 256 + threadIdx.x;
    int KN = K * N;
    int l = idx / KN, rem = idx % KN;
    int n = rem / K, k = rem % K;
    dst[idx] = f2b(src[(long)l * KN + (long)k * N + n]);
}

// Fused QKV weight transpose: dst [10][384][128]
__global__ void wtr_qkv_k(const float* __restrict__ Wq, const float* __restrict__ Wk,
                          const float* __restrict__ Wv, ushort* __restrict__ dst) {
    int idx = blockIdx.x * 256 + threadIdx.x;   // 491520
    int l = idx / (384 * 128);
    int rem = idx % (384 * 128);
    int n = rem >> 7, k = rem & 127;
    const float* src = (n < 128) ? Wq : (n < 256) ? Wk : Wv;
    dst[idx] = f2b(src[l * 16384 + k * 128 + (n & 127)]);
}

__global__ void bcat_k(const float* __restrict__ bq, const float* __restrict__ bk,
                       const float* __restrict__ bv, float* __restrict__ dst) {
    int idx = blockIdx.x * 256 + threadIdx.x;   // 3840
    int l = idx / 384, n = idx % 384;
    const float* s = (n < 128) ? bq : (n < 256) ? bk : bv;
    dst[idx] = s[l * 128 + (n & 127)];
}

// ---------------------------------------------------------------------------
// LayerNorm: one wave per 128-row; 4 rows/block (entry + layer-4 path only).
template <bool OBF>
__global__ __launch_bounds__(256) void ln_k(const float* __restrict__ in,
                                            const float* __restrict__ g,
                                            const float* __restrict__ bta,
                                            void* outp) {
    int wave = threadIdx.x >> 6;
    int lane = threadIdx.x & 63;
    long row = (long)blockIdx.x * 4 + wave;
    const float* r = in + row * D_;
    float2 v = *(const float2*)(r + lane * 2);
    float sum = v.x + v.y;
    float sq  = v.x * v.x + v.y * v.y;
    #pragma unroll
    for (int o = 32; o; o >>= 1) { sum += __shfl_xor(sum, o); sq += __shfl_xor(sq, o); }
    float mean = sum * (1.0f / D_);
    float var  = sq * (1.0f / D_) - mean * mean;
    float inv  = rsqrtf(var + 1e-5f);
    float2 gv = *(const float2*)(g + lane * 2);
    float2 bv = *(const float2*)(bta + lane * 2);
    float o0 = gv.x * (v.x - mean) * inv + bv.x;
    float o1 = gv.y * (v.y - mean) * inv + bv.y;
    if (OBF) {
        uint packed = (uint)f2b(o0) | ((uint)f2b(o1) << 16);
        *(uint*)((ushort*)outp + row * D_ + lane * 2) = packed;
    } else {
        float2 ov; ov.x = o0; ov.y = o1;
        *(float2*)((float*)outp + row * D_ + lane * 2) = ov;
    }
}

// ---------------------------------------------------------------------------
// MFMA bf16 GEMM, BN=64 (qkv / ff1). Unchanged, proven.
template <bool OBF, bool GELU, bool RESID>
__global__ __launch_bounds__(256) void gemm_k2(const ushort* __restrict__ A,
                                               const ushort* __restrict__ Wt,
                                               const float* __restrict__ bias,
                                               const float* res,
                                               void* outp,
                                               int K, int N) {
    __shared__ ushort Al[128 * 128];
    __shared__ ushort Bl[64 * 128];
    const int tid = threadIdx.x;
    const int lane = tid & 63, wid = tid >> 6;
    const int lr = lane & 15, lh = lane >> 4;
    const int wr = wid >> 1, wc = wid & 1;
    const long row0 = (long)blockIdx.x * 128;
    const int  col0 = blockIdx.y * 64;

    f32x4 acc[4][2];
    #pragma unroll
    for (int i = 0; i < 4; ++i)
        #pragma unroll
        for (int j = 0; j < 2; ++j) { f32x4 z = {0.f, 0.f, 0.f, 0.f}; acc[i][j] = z; }

    for (int k0 = 0; k0 < K; k0 += 128) {
        #pragma unroll
        for (int i = 0; i < 8; ++i) {
            int idx = i * 256 + tid;
            int r = idx >> 4, s = idx & 15;
            uint4 d = *(const uint4*)(A + (row0 + r) * (long)K + k0 + s * 8);
            int w = (r * 128 + s * 8) ^ ((r & 7) << 3);
            *(uint4*)&Al[w] = d;
        }
        #pragma unroll
        for (int i = 0; i < 4; ++i) {
            int idx = i * 256 + tid;
            int r = idx >> 4, s = idx & 15;
            uint4 d = *(const uint4*)(Wt + (col0 + r) * (long)K + k0 + s * 8);
            int w = (r * 128 + s * 8) ^ ((r & 7) << 3);
            *(uint4*)&Bl[w] = d;
        }
        __syncthreads();
        #pragma unroll
        for (int ks = 0; ks < 4; ++ks) {
            bf16x8 af[4], bfr[2];
            #pragma unroll
            for (int fi = 0; fi < 4; ++fi) {
                int r = (wr << 6) + (fi << 4) + lr;
                int w = (r * 128 + ((ks << 2) + lh) * 8) ^ ((r & 7) << 3);
                af[fi] = *(const bf16x8*)&Al[w];
            }
            #pragma unroll
            for (int fj = 0; fj < 2; ++fj) {
                int c = (wc << 5) + (fj << 4) + lr;
                int w = (c * 128 + ((ks << 2) + lh) * 8) ^ ((c & 7) << 3);
                bfr[fj] = *(const bf16x8*)&Bl[w];
            }
            #pragma unroll
            for (int fi = 0; fi < 4; ++fi)
                #pragma unroll
                for (int fj = 0; fj < 2; ++fj)
                    acc[fi][fj] = __builtin_amdgcn_mfma_f32_16x16x32_bf16(
                        af[fi], bfr[fj], acc[fi][fj], 0, 0, 0);
        }
        __syncthreads();
    }

    #pragma unroll
    for (int fi = 0; fi < 4; ++fi) {
        #pragma unroll
        for (int fj = 0; fj < 2; ++fj) {
            int col = col0 + (wc << 5) + (fj << 4) + lr;
            float bv = bias[col];
            #pragma unroll
            for (int rg = 0; rg < 4; ++rg) {
                long row = row0 + (wr << 6) + (fi << 4) + lh * 4 + rg;
                float val = acc[fi][fj][rg] + bv;
                if (GELU) val = 0.5f * val * (1.0f + erff(val * 0.70710678f));
                if (RESID) val += res[row * (long)N + col];
                if (OBF) ((ushort*)outp)[row * (long)N + col] = f2b(val);
                else     ((float*)outp)[row * (long)N + col] = val;
            }
        }
    }
}

// ---------------------------------------------------------------------------
// MFMA bf16 GEMM, BN=128 full-row, fused {bias, +res, x-write, LayerNorm}.
// 4 waves row-split: wave owns 32 rows x 128 cols -> each row entirely within
// one 16-lane group => in-register LN (in-thread over 8 col-frags + shfl over lr).
// LNMODE: 0 = write x only; 1 = write x f32 + h bf16 = LN(x; g,b);
//         2 = write x f32 = LN(val; g,b)  (norm2 overwrite).
template <int LNMODE>
__global__ __launch_bounds__(256) void gemm_k3(const ushort* __restrict__ A,
                                               const ushort* __restrict__ Wt,
                                               const float* __restrict__ bias,
                                               const float* __restrict__ res,
                                               float* __restrict__ xout,
                                               ushort* __restrict__ hout,
                                               const float* __restrict__ lng,
                                               const float* __restrict__ lnb,
                                               int K) {
    __shared__ ushort Al[128 * 128];
    __shared__ ushort Bl[128 * 128];
    const int tid = threadIdx.x;
    const int lane = tid & 63, wid = tid >> 6;
    const int lr = lane & 15, lh = lane >> 4;
    const long row0 = (long)blockIdx.x * 128;

    f32x4 acc[2][8];
    #pragma unroll
    for (int i = 0; i < 2; ++i)
        #pragma unroll
        for (int j = 0; j < 8; ++j) { f32x4 z = {0.f, 0.f, 0.f, 0.f}; acc[i][j] = z; }

    for (int k0 = 0; k0 < K; k0 += 128) {
        #pragma unroll
        for (int i = 0; i < 8; ++i) {
            int idx = i * 256 + tid;
            int r = idx >> 4, s = idx & 15;
            uint4 d = *(const uint4*)(A + (row0 + r) * (long)K + k0 + s * 8);
            int w = (r * 128 + s * 8) ^ ((r & 7) << 3);
            *(uint4*)&Al[w] = d;
        }
        #pragma unroll
        for (int i = 0; i < 8; ++i) {
            int idx = i * 256 + tid;
            int r = idx >> 4, s = idx & 15;   // r = output col 0..127
            uint4 d = *(const uint4*)(Wt + r * (long)K + k0 + s * 8);
            int w = (r * 128 + s * 8) ^ ((r & 7) << 3);
            *(uint4*)&Bl[w] = d;
        }
        __syncthreads();
        #pragma unroll
        for (int ks = 0; ks < 4; ++ks) {
            bf16x8 af[2], bfr[8];
            #pragma unroll
            for (int fi = 0; fi < 2; ++fi) {
                int r = (wid << 5) + (fi << 4) + lr;
                int w = (r * 128 + ((ks << 2) + lh) * 8) ^ ((r & 7) << 3);
                af[fi] = *(const bf16x8*)&Al[w];
            }
            #pragma unroll
            for (int fj = 0; fj < 8; ++fj) {
                int c = (fj << 4) + lr;
                int w = (c * 128 + ((ks << 2) + lh) * 8) ^ ((c & 7) << 3);
                bfr[fj] = *(const bf16x8*)&Bl[w];
            }
            #pragma unroll
            for (int fi = 0; fi < 2; ++fi)
                #pragma unroll
                for (int fj = 0; fj < 8; ++fj)
                    acc[fi][fj] = __builtin_amdgcn_mfma_f32_16x16x32_bf16(
                        af[fi], bfr[fj], acc[fi][fj], 0, 0, 0);
        }
        __syncthreads();
    }

    // Epilogue: row = row0 + wid*32 + fi*16 + lh*4 + rg; cols = fj*16 + lr.
    #pragma unroll
    for (int fi = 0; fi < 2; ++fi) {
        #pragma unroll
        for (int rg = 0; rg < 4; ++rg) {
            long row = row0 + (wid << 5) + (fi << 4) + (lh << 2) + rg;
            float v[8], s1 = 0.f, s2 = 0.f;
            #pragma unroll
            for (int fj = 0; fj < 8; ++fj) {
                int col = (fj << 4) + lr;
                float val = acc[fi][fj][rg] + bias[col] + res[row * 128 + col];
                v[fj] = val; s1 += val; s2 += val * val;
            }
            if (LNMODE == 0) {
                #pragma unroll
                for (int fj = 0; fj < 8; ++fj)
                    xout[row * 128 + ((fj << 4) + lr)] = v[fj];
            } else {
                #pragma unroll
                for (int o = 1; o < 16; o <<= 1) {
                    s1 += __shfl_xor(s1, o);
                    s2 += __shfl_xor(s2, o);
                }
                float mean = s1 * (1.0f / 128.0f);
                float var  = s2 * (1.0f / 128.0f) - mean * mean;
                float inv  = rsqrtf(var + 1e-5f);
                #pragma unroll
                for (int fj = 0; fj < 8; ++fj) {
                    int col = (fj << 4) + lr;
                    float ln = lng[col] * (v[fj] - mean) * inv + lnb[col];
                    if (LNMODE == 1) {
                        xout[row * 128 + col] = v[fj];
                        hout[row * 128 + col] = f2b(ln);
                    } else {
                        xout[row * 128 + col] = ln;
                    }
                }
            }
        }
    }
}

// ---------------------------------------------------------------------------
// MFMA attention (unchanged from round 4, proven).
__device__ __forceinline__ int lds_e(int s, int c) {
    return s * 128 + (c ^ ((s & 7) << 3));
}

__global__ __launch_bounds__(512) void attn3_k(const ushort* __restrict__ qkv,
                                               const uint* __restrict__ mb,
                                               ushort* __restrict__ o) {
    __shared__ ushort ks[S_ * 128];
    __shared__ ushort vs[S_ * 128];
    const int b = blockIdx.x, tid = threadIdx.x;
    const long base = (long)b * S_ * 384;

    for (int idx = tid; idx < S_ * 16; idx += 512) {
        int r = idx >> 4, sl = idx & 15;
        uint4 uk = *(const uint4*)(qkv + base + (long)r * 384 + 128 + sl * 8);
        uint4 uv = *(const uint4*)(qkv + base + (long)r * 384 + 256 + sl * 8);
        int w = lds_e(r, sl * 8);
        *(uint4*)&ks[w] = uk;
        *(uint4*)&vs[w] = uv;
    }
    __syncthreads();

    const int h = tid >> 6;
    const int lane = tid & 63;
    const int lr = lane & 15, lh = lane >> 4;
    const int lh2 = lh & 1;

    bf16x8 kf[12];
    #pragma unroll
    for (int jt = 0; jt < 12; ++jt) {
        int j = jt * 16 + lr; if (j > 189) j = 189;
        bf16x8 v8 = *(const bf16x8*)&ks[lds_e(j, h * 16 + lh2 * 8)];
        if (lh >= 2) { bf16x8 z = {0,0,0,0,0,0,0,0}; v8 = z; }
        kf[jt] = v8;
    }
    bf16x4 vf[12];
    #pragma unroll
    for (int jt = 0; jt < 12; ++jt) {
        int j0 = jt * 16 + lh * 4;
        int c = h * 16 + lr;
        int ja = j0 + 0 > 189 ? 189 : j0 + 0;
        int jb = j0 + 1 > 189 ? 189 : j0 + 1;
        int jc = j0 + 2 > 189 ? 189 : j0 + 2;
        int jd = j0 + 3 > 189 ? 189 : j0 + 3;
        bf16x4 v4;
        v4[0] = (short)vs[lds_e(ja, c)];
        v4[1] = (short)vs[lds_e(jb, c)];
        v4[2] = (short)vs[lds_e(jc, c)];
        v4[3] = (short)vs[lds_e(jd, c)];
        vf[jt] = v4;
    }

    int sq = lr;
    bf16x8 qf = *(const bf16x8*)(qkv + base + (long)sq * 384 + h * 16 + lh2 * 8);

    for (int qt = 0; qt < 12; ++qt) {
        f32x4 T[12];
        f32x4 zero = {0.f, 0.f, 0.f, 0.f};
        #pragma unroll
        for (int jt = 0; jt < 12; ++jt)
            T[jt] = __builtin_amdgcn_mfma_f32_16x16x32_bf16(kf[jt], qf, zero, 0, 0, 0);

        {
            int sn = (qt + 1) * 16 + lr; if (sn > 189) sn = 189;
            qf = *(const bf16x8*)(qkv + base + (long)sn * 384 + h * 16 + lh2 * 8);
        }

        int qc = qt * 16 + lr; if (qc > 189) qc = 189;
        uint mw[6];
        #pragma unroll
        for (int w = 0; w < 6; ++w) mw[w] = mb[qc * 8 + w];

        float p[12][4];
        float lsum = 0.f;
        #pragma unroll
        for (int jt = 0; jt < 12; ++jt) {
            uint word = mw[jt >> 1];
            #pragma unroll
            for (int r = 0; r < 4; ++r) {
                int bit = ((jt & 1) << 4) + 4 * lh + r;
                float e = __expf(T[jt][r] * 0.25f);
                float pv = ((word >> bit) & 1u) ? e : 0.f;
                p[jt][r] = pv;
                lsum += pv;
            }
        }
        lsum += __shfl_xor(lsum, 16);
        lsum += __shfl_xor(lsum, 32);
        float inv = 1.0f / lsum;

        f32x4 acc = {0.f, 0.f, 0.f, 0.f};
        #pragma unroll
        for (int jt = 0; jt < 12; ++jt) {
            uint lo, hi;
            float a0 = p[jt][0] * inv, a1 = p[jt][1] * inv;
            float a2 = p[jt][2] * inv, a3 = p[jt][3] * inv;
            asm("v_cvt_pk_bf16_f32 %0, %1, %2" : "=v"(lo) : "v"(a0), "v"(a1));
            asm("v_cvt_pk_bf16_f32 %0, %1, %2" : "=v"(hi) : "v"(a2), "v"(a3));
            uint2 u; u.x = lo; u.y = hi;
            bf16x4 pf = *(bf16x4*)&u;
            asm("s_nop 1\n\tv_mfma_f32_16x16x16_bf16 %0, %1, %2, %0"
                : "+v"(acc) : "v"(pf), "v"(vf[jt]));
        }
        asm volatile("s_nop 7\n\ts_nop 7" : "+v"(acc));

        #pragma unroll
        for (int r = 0; r < 4; ++r) {
            int qg = qt * 16 + 4 * lh + r;
            if (qg < S_)
                o[((long)b * S_ + qg) * 128 + h * 16 + lr] = f2b(acc[r]);
        }
    }
}

// ---------------------------------------------------------------------------
__global__ __launch_bounds__(256) void fin_k(const float* __restrict__ x,
                                             const float* __restrict__ g,
                                             const float* __restrict__ bta,
                                             const float* __restrict__ fw,
                                             const float* __restrict__ fb,
                                             float* __restrict__ t) {
    int wave = threadIdx.x >> 6;
    int lane = threadIdx.x & 63;
    long row = (long)blockIdx.x * 4 + wave;
    const float* r = x + row * D_;
    float2 v = *(const float2*)(r + lane * 2);
    float sum = v.x + v.y;
    float sq  = v.x * v.x + v.y * v.y;
    #pragma unroll
    for (int o = 32; o; o >>= 1) { sum += __shfl_xor(sum, o); sq += __shfl_xor(sq, o); }
    float mean = sum * (1.0f / D_);
    float var  = sq * (1.0f / D_) - mean * mean;
    float inv  = rsqrtf(var + 1e-5f);
    float2 gv = *(const float2*)(g + lane * 2);
    float2 bv = *(const float2*)(bta + lane * 2);
    float y0 = gv.x * (v.x - mean) * inv + bv.x;
    float y1 = gv.y * (v.y - mean) * inv + bv.y;
    float part = y0 * fw[lane * 2] + y1 * fw[lane * 2 + 1];
    #pragma unroll
    for (int o = 32; o; o >>= 1) part += __shfl_xor(part, o);
    if (lane == 0) t[row] = part + fb[0];
}

__global__ __launch_bounds__(128) void outgemm_k(const float* __restrict__ t,
                                                 const float* __restrict__ ow,
                                                 const float* __restrict__ ob,
                                                 float* __restrict__ out) {
    __shared__ float ts[S_];
    int b = blockIdx.x, tid = threadIdx.x;
    for (int i = tid; i < S_; i += 128) ts[i] = t[(long)b * S_ + i];
    __syncthreads();
    if (tid < CN_) {
        float acc = ob[tid];
        for (int s = 0; s < S_; ++s) acc = fmaf(ts[s], ow[s * CN_ + tid], acc);
        out[(long)b * CN_ + tid] = acc;
    }
}

// ---------------------------------------------------------------------------
extern "C" void kernel_launch(void* const* d_in, const int* in_sizes, int n_in,
                              void* d_out, int out_size, void* d_ws, size_t ws_size,
                              hipStream_t stream) {
    const float* mag  = (const float*)d_in[0];
    const float* syn  = (const float*)d_in[1];
    const int*   pc   = (const int*)  d_in[2];
    const float* se   = (const float*)d_in[3];
    const float* Wq   = (const float*)d_in[4];
    const float* bq   = (const float*)d_in[5];
    const float* Wk   = (const float*)d_in[6];
    const float* bk   = (const float*)d_in[7];
    const float* Wv   = (const float*)d_in[8];
    const float* bv   = (const float*)d_in[9];
    const float* Wo   = (const float*)d_in[10];
    const float* bo   = (const float*)d_in[11];
    const float* W1   = (const float*)d_in[12];
    const float* b1   = (const float*)d_in[13];
    const float* W2   = (const float*)d_in[14];
    const float* b2   = (const float*)d_in[15];
    const float* ln1g = (const float*)d_in[16];
    const float* ln1b = (const float*)d_in[17];
    const float* ln2g = (const float*)d_in[18];
    const float* ln2b = (const float*)d_in[19];
    const float* encg = (const float*)d_in[20];
    const float* encb = (const float*)d_in[21];
    const float* n2g  = (const float*)d_in[22];
    const float* n2b  = (const float*)d_in[23];
    const float* finw = (const float*)d_in[24];
    const float* finb = (const float*)d_in[25];
    const float* outw = (const float*)d_in[26];
    const float* outb = (const float*)d_in[27];
    float* out = (float*)d_out;

    // Workspace layout (bytes), total ~170.4 MiB
    char* p = (char*)d_ws;
    float*  x     = (float*) p;                      // x f32 [MR][128]
    ushort* h     = (ushort*)(p + 49807360);         // h bf16 (o aliases)
    ushort* qkv   = (ushort*)(p + 74711040);         // qkv bf16 [MR][384] / ff1 [MR][512]
    ushort* Wqkvt = (ushort*)(p + 174325760);        // [10][384][128]
    ushort* Wot   = (ushort*)(p + 175308800);        // [10][128][128]
    ushort* W1t   = (ushort*)(p + 175636480);        // [10][512][128]
    ushort* W2t   = (ushort*)(p + 176947200);        // [10][128][512]
    float*  bqkv  = (float*) (p + 178257920);        // [10][384]
    uint*   mb    = (uint*)  (p + 178273280);        // [190][8]
    float*  t     = (float*) (p + 178279360);        // [MR]
    ushort* o     = h;
    ushort* ff1   = qkv;

    mbits2_k<<<1, 256, 0, stream>>>(pc, mb);
    embed_k<<<(int)(((long)MR_ * D_ + 255) / 256), 256, 0, stream>>>(mag, syn, se, x);
    wtr_qkv_k<<<1920, 256, 0, stream>>>(Wq, Wk, Wv, Wqkvt);
    wtr_k<<<640, 256, 0, stream>>>(Wo, Wot, 128, 128);
    wtr_k<<<2560, 256, 0, stream>>>(W1, W1t, 128, 512);
    wtr_k<<<2560, 256, 0, stream>>>(W2, W2t, 512, 128);
    bcat_k<<<15, 256, 0, stream>>>(bq, bk, bv, bqkv);

    // Entry LN (layer 0's ln1)
    ln_k<true><<<MR_ / 4, 256, 0, stream>>>(x, ln1g, ln1b, h);

    for (int i = 0; i < NDEC_; ++i) {
        gemm_k2<true, false, false><<<dim3(760, 6), 256, 0, stream>>>(
            h, Wqkvt + (long)i * 49152, bqkv + i * 384, nullptr, qkv, 128, 384);
        attn3_k<<<B_, 512, 0, stream>>>(qkv, mb, o);
        // o-proj fused: x += o@Wo + bo; h = LN(x; ln2_i)
        gemm_k3<1><<<760, 256, 0, stream>>>(
            o, Wot + (long)i * 16384, bo + i * 128, x, x, h,
            ln2g + i * 128, ln2b + i * 128, 128);
        gemm_k2<true, true, false><<<dim3(760, 8), 256, 0, stream>>>(
            h, W1t + (long)i * 65536, b1 + i * 512, nullptr, ff1, 128, 512);
        // ff2 fused
        if (i == 4) {
            // x = LN(x + ff; n2), then standalone ln1_5 -> h
            gemm_k3<2><<<760, 256, 0, stream>>>(
                ff1, W2t + (long)i * 65536, b2 + i * 128, x, x, nullptr,
                n2g, n2b, 512);
            ln_k<true><<<MR_ / 4, 256, 0, stream>>>(x, ln1g + 5 * 128, ln1b + 5 * 128, h);
        } else if (i == NDEC_ - 1) {
            gemm_k3<0><<<760, 256, 0, stream>>>(
                ff1, W2t + (long)i * 65536, b2 + i * 128, x, x, nullptr,
                nullptr, nullptr, 512);
        } else {
            // x += ff; h = LN(x; ln1_{i+1})
            gemm_k3<1><<<760, 256, 0, stream>>>(
                ff1, W2t + (long)i * 65536, b2 + i * 128, x, x, h,
                ln1g + (i + 1) * 128, ln1b + (i + 1) * 128, 512);
        }
    }

    fin_k<<<MR_ / 4, 256, 0, stream>>>(x, encg, encb, finw, finb, t);
    outgemm_k<<<B_, 128, 0, stream>>>(t, outw, outb, out);
}